// Round 3
// baseline (665.044 us; speedup 1.0000x reference)
//
#include <hip/hip_runtime.h>

typedef unsigned short u16;
typedef unsigned int   u32;
typedef __attribute__((ext_vector_type(8))) short short8;
typedef __attribute__((ext_vector_type(4))) float f32x4;
typedef __attribute__((ext_vector_type(4))) u32   u32x4;
typedef __attribute__((ext_vector_type(2))) u32   u32x2;

#define MFMA16 __builtin_amdgcn_mfma_f32_16x16x32_bf16

__device__ __forceinline__ u16 f2bf(float f) {           // rne
  u32 u = __float_as_uint(f);
  return (u16)((u + 0x7FFFu + ((u >> 16) & 1u)) >> 16);
}
__device__ __forceinline__ u32 cvtpk(float a, float b) { // {lo:bf16(a), hi:bf16(b)}
  u32 d; asm("v_cvt_pk_bf16_f32 %0, %1, %2" : "=v"(d) : "v"(a), "v"(b)); return d;
}
__device__ __forceinline__ void split2(float a, float b, u32& hi, u32& lo) {
  u32 ua = __float_as_uint(a), ub = __float_as_uint(b);
  hi = __builtin_amdgcn_perm(ub, ua, 0x07060302u);       // {trunc(a), trunc(b)}
  lo = cvtpk(a - __uint_as_float(ua & 0xFFFF0000u), b - __uint_as_float(ub & 0xFFFF0000u));
}
__device__ __forceinline__ void gload16(const void* g, void* l) {
  __builtin_amdgcn_global_load_lds(
      (const __attribute__((address_space(1))) void*)g,
      (__attribute__((address_space(3))) void*)l, 16, 0, 0);
}

// ---------------------------------------------------------------------------
// prep_x: x[512][65536] fp32 -> xT[65536][512] bf16 hi(trunc)/lo(rne).
// Tile 32k x 256n via LDS. Grid 4096 (16 k-tiles x 256 n-tiles).
// ---------------------------------------------------------------------------
__global__ __launch_bounds__(256)
void prep_x(const float* __restrict__ x, u16* __restrict__ xhi, u16* __restrict__ xlo)
{
  __shared__ float tile[32 * 260];
  const int bk = blockIdx.x & 15, bn = blockIdx.x >> 4;
  const int t = threadIdx.x;
  const int cw = (t & 63) * 4, rw = (t >> 6) * 8;
#pragma unroll
  for (int it = 0; it < 8; ++it) {
    const int r = rw + it;
    f32x4 v = *(const f32x4*)(x + (size_t)(bk * 32 + r) * 65536 + (size_t)bn * 256 + cw);
    *(f32x4*)&tile[r * 260 + cw] = v;
  }
  __syncthreads();
  const int n = t;
  u32 hi[16], lo[16];
#pragma unroll
  for (int q = 0; q < 16; ++q)
    split2(tile[(2 * q) * 260 + n], tile[(2 * q + 1) * 260 + n], hi[q], lo[q]);
  const size_t ob = (size_t)(bn * 256 + n) * 512 + bk * 32;
#pragma unroll
  for (int c4 = 0; c4 < 4; ++c4) {
    *(u32x4*)(xhi + ob + c4 * 8) = (u32x4){hi[4*c4], hi[4*c4+1], hi[4*c4+2], hi[4*c4+3]};
    *(u32x4*)(xlo + ob + c4 * 8) = (u32x4){lo[4*c4], lo[4*c4+1], lo[4*c4+2], lo[4*c4+3]};
  }
}

// ---------------------------------------------------------------------------
// conv_fg: EMU bf16-pair GEMM, M=1024 (f rows 0-511, g rows 512-1023), K=512.
// B staged by global_load_lds from xT (g-blocks: sigma-permuted rows so the
// output lands as gT[c][j][k'] with coalesced writes). A reg-staged (tiny).
// ---------------------------------------------------------------------------
__global__ __launch_bounds__(256)
void conv_fg(const float* __restrict__ Wf, const float* __restrict__ Wg,
             const u16* __restrict__ xhi, const u16* __restrict__ xlo,
             u16* __restrict__ fhi, u16* __restrict__ flo,
             u16* __restrict__ gThi, u16* __restrict__ gTlo)
{
  constexpr int AP = 40;                       // padded A pitch (u16)
  __shared__ u16 sAh[128 * AP], sAl[128 * AP]; // 10 KB each
  __shared__ u16 sBh[128 * 32], sBl[128 * 32]; // 8 KB each, linear (gload_lds)
  const int bid = blockIdx.x;
  const int wg = (bid & 7) * 512 + (bid >> 3); // XCD swizzle, 4096%8==0
  const int tm = wg >> 9, tn = wg & 511;
  const int t = threadIdx.x, lane = t & 63, wid = t >> 6;
  const int wr = wid >> 1, wc = wid & 1, lr = lane & 15, lq = lane >> 4;
  const bool gmode = tm >= 4;
  const float* Asrc = gmode ? (Wg + (size_t)(tm - 4) * 128 * 512)
                            : (Wf + (size_t)tm * 128 * 512);
  const int am = t >> 1, akh = (t & 1) << 4;   // A reg-stage mapping
  const int brl = t >> 2, bko = t & 3;         // B gload mapping
  const int ldsb = wid * 1024;

  f32x4 acc[4][4];
#pragma unroll
  for (int i = 0; i < 4; ++i)
#pragma unroll
    for (int j = 0; j < 4; ++j) acc[i][j] = (f32x4){0.f, 0.f, 0.f, 0.f};

  for (int k0 = 0; k0 < 512; k0 += 32) {
    // ---- B: 4x global_load_lds (hi/lo x 2 halves)
#pragma unroll
    for (int q = 0; q < 2; ++q) {
      const int row = q * 64 + brl;
      size_t gr;
      if (!gmode) gr = (size_t)(tn * 128 + row);
      else        gr = (size_t)(((tn & 1) << 7) + row) * 256 + (tn >> 1);
      const size_t off = gr * 512 + k0 + bko * 8;
      gload16(xhi + off, (char*)sBh + q * 4096 + ldsb);
      gload16(xlo + off, (char*)sBl + q * 4096 + ldsb);
    }
    // ---- A: reg-staged split (128x32 fp32 = tiny)
    {
      const float* ap = Asrc + (size_t)am * 512 + k0 + akh;
      float v[16];
#pragma unroll
      for (int c4 = 0; c4 < 4; ++c4) {
        f32x4 w = *(const f32x4*)(ap + 4 * c4);
        v[4*c4] = w[0]; v[4*c4+1] = w[1]; v[4*c4+2] = w[2]; v[4*c4+3] = w[3];
      }
      u32 hi[8], lo[8];
#pragma unroll
      for (int q = 0; q < 8; ++q) split2(v[2*q], v[2*q+1], hi[q], lo[q]);
      *(u32x4*)(sAh + am * AP + akh)     = (u32x4){hi[0], hi[1], hi[2], hi[3]};
      *(u32x4*)(sAh + am * AP + akh + 8) = (u32x4){hi[4], hi[5], hi[6], hi[7]};
      *(u32x4*)(sAl + am * AP + akh)     = (u32x4){lo[0], lo[1], lo[2], lo[3]};
      *(u32x4*)(sAl + am * AP + akh + 8) = (u32x4){lo[4], lo[5], lo[6], lo[7]};
    }
    __syncthreads();
    short8 ah[4], al[4], bh[4], bl[4];
#pragma unroll
    for (int mi = 0; mi < 4; ++mi) {
      ah[mi] = *(const short8*)(sAh + (wr * 64 + mi * 16 + lr) * AP + lq * 8);
      al[mi] = *(const short8*)(sAl + (wr * 64 + mi * 16 + lr) * AP + lq * 8);
    }
#pragma unroll
    for (int ni = 0; ni < 4; ++ni) {
      bh[ni] = *(const short8*)(sBh + (wc * 64 + ni * 16 + lr) * 32 + lq * 8);
      bl[ni] = *(const short8*)(sBl + (wc * 64 + ni * 16 + lr) * 32 + lq * 8);
    }
#pragma unroll
    for (int mi = 0; mi < 4; ++mi)
#pragma unroll
      for (int ni = 0; ni < 4; ++ni) {
        acc[mi][ni] = MFMA16(ah[mi], bh[ni], acc[mi][ni], 0, 0, 0);
        acc[mi][ni] = MFMA16(ah[mi], bl[ni], acc[mi][ni], 0, 0, 0);
        acc[mi][ni] = MFMA16(al[mi], bh[ni], acc[mi][ni], 0, 0, 0);
      }
    __syncthreads();
  }

  const int cch = (gmode ? (tm - 4) : tm) * 128 + wr * 64;
  const int cbase = tn * 128 + wc * 64;
  u16* dsthi = gmode ? gThi : fhi;
  u16* dstlo = gmode ? gTlo : flo;
#pragma unroll
  for (int mi = 0; mi < 4; ++mi)
#pragma unroll
    for (int ni = 0; ni < 4; ++ni) {
      const int r0 = cch + mi * 16 + lq * 4;
      const int cc = cbase + ni * 16 + lr;
#pragma unroll
      for (int r = 0; r < 4; ++r) {
        float val = acc[mi][ni][r];
        u32 u = __float_as_uint(val);
        const size_t idx = (size_t)(r0 + r) * 65536 + cc;
        dsthi[idx] = (u16)(u >> 16);
        dstlo[idx] = f2bf(val - __uint_as_float(u & 0xFFFF0000u));
      }
    }
}

// ---------------------------------------------------------------------------
// conv_h: plain bf16 GEMM, h = rne(Wh) @ xT_hi. M=512, K=512, out bf16.
// ---------------------------------------------------------------------------
__global__ __launch_bounds__(256)
void conv_h(const float* __restrict__ Wh, const u16* __restrict__ xhi,
            u16* __restrict__ hb)
{
  constexpr int AP = 40;
  __shared__ u16 sA[128 * AP];
  __shared__ u16 sB[128 * 32];
  const int bid = blockIdx.x;
  const int wg = (bid & 7) * 256 + (bid >> 3); // 2048%8==0
  const int tm = wg >> 9, tn = wg & 511;
  const int t = threadIdx.x, lane = t & 63, wid = t >> 6;
  const int wr = wid >> 1, wc = wid & 1, lr = lane & 15, lq = lane >> 4;
  const int am = t >> 1, akh = (t & 1) << 4;
  const int brl = t >> 2, bko = t & 3;
  const int ldsb = wid * 1024;

  f32x4 acc[4][4];
#pragma unroll
  for (int i = 0; i < 4; ++i)
#pragma unroll
    for (int j = 0; j < 4; ++j) acc[i][j] = (f32x4){0.f, 0.f, 0.f, 0.f};

  for (int k0 = 0; k0 < 512; k0 += 32) {
#pragma unroll
    for (int q = 0; q < 2; ++q) {
      const size_t off = (size_t)(tn * 128 + q * 64 + brl) * 512 + k0 + bko * 8;
      gload16(xhi + off, (char*)sB + q * 4096 + ldsb);
    }
    {
      const float* ap = Wh + (size_t)(tm * 128 + am) * 512 + k0 + akh;
      float v[16];
#pragma unroll
      for (int c4 = 0; c4 < 4; ++c4) {
        f32x4 w = *(const f32x4*)(ap + 4 * c4);
        v[4*c4] = w[0]; v[4*c4+1] = w[1]; v[4*c4+2] = w[2]; v[4*c4+3] = w[3];
      }
      u32 h8[8];
#pragma unroll
      for (int q = 0; q < 8; ++q) h8[q] = cvtpk(v[2*q], v[2*q+1]);
      *(u32x4*)(sA + am * AP + akh)     = (u32x4){h8[0], h8[1], h8[2], h8[3]};
      *(u32x4*)(sA + am * AP + akh + 8) = (u32x4){h8[4], h8[5], h8[6], h8[7]};
    }
    __syncthreads();
    short8 af[4], bfr[4];
#pragma unroll
    for (int mi = 0; mi < 4; ++mi)
      af[mi] = *(const short8*)(sA + (wr * 64 + mi * 16 + lr) * AP + lq * 8);
#pragma unroll
    for (int ni = 0; ni < 4; ++ni)
      bfr[ni] = *(const short8*)(sB + (wc * 64 + ni * 16 + lr) * 32 + lq * 8);
#pragma unroll
    for (int mi = 0; mi < 4; ++mi)
#pragma unroll
      for (int ni = 0; ni < 4; ++ni)
        acc[mi][ni] = MFMA16(af[mi], bfr[ni], acc[mi][ni], 0, 0, 0);
    __syncthreads();
  }
  const int rb = tm * 128 + wr * 64, cbase = tn * 128 + wc * 64;
#pragma unroll
  for (int mi = 0; mi < 4; ++mi)
#pragma unroll
    for (int ni = 0; ni < 4; ++ni) {
      const int r0 = rb + mi * 16 + lq * 4, cc = cbase + ni * 16 + lr;
#pragma unroll
      for (int r = 0; r < 4; ++r)
        hb[(size_t)(r0 + r) * 65536 + cc] = f2bf(acc[mi][ni][r]);
    }
}

// ---------------------------------------------------------------------------
// scores: per (c, j-half): S-tile = f[c](256 x K) @ gT[c](128 x K)^T, EMU.
// Full softmax columns in-block -> writes normalized PT[c][j][i] bf16.
// 512 threads (8 waves, 4 row x 2 col).
// ---------------------------------------------------------------------------
__global__ __launch_bounds__(512)
void scores_kernel(const u16* __restrict__ fhi, const u16* __restrict__ flo,
                   const u16* __restrict__ gThi, const u16* __restrict__ gTlo,
                   u16* __restrict__ Pt)
{
  __shared__ u16 sAh[256 * 32], sAl[256 * 32]; // 16 KB each
  __shared__ u16 sBh[128 * 32], sBl[128 * 32]; // 8 KB each
  __shared__ float cmax[4][128], csum[4][128];
  const int bid = blockIdx.x;
  const int wg = (bid & 7) * 128 + (bid >> 3); // 1024%8==0
  const int c = wg >> 1, jt = wg & 1;
  const int t = threadIdx.x, lane = t & 63, wid = t >> 6;
  const int wr = wid >> 1, wc = wid & 1, lr = lane & 15, lq = lane >> 4;
  const size_t cb = (size_t)c * 65536;
  const int grl = t >> 2, gko = t & 3;
  const int ldsb = wid * 1024;

  f32x4 acc[4][4];
#pragma unroll
  for (int i = 0; i < 4; ++i)
#pragma unroll
    for (int j = 0; j < 4; ++j) acc[i][j] = (f32x4){0.f, 0.f, 0.f, 0.f};

  for (int k0 = 0; k0 < 256; k0 += 32) {
#pragma unroll
    for (int q = 0; q < 2; ++q) {
      const size_t off = cb + (size_t)(q * 128 + grl) * 256 + k0 + gko * 8;
      gload16(fhi + off, (char*)sAh + q * 8192 + ldsb);
      gload16(flo + off, (char*)sAl + q * 8192 + ldsb);
    }
    {
      const size_t off = cb + (size_t)(jt * 128 + grl) * 256 + k0 + gko * 8;
      gload16(gThi + off, (char*)sBh + ldsb);
      gload16(gTlo + off, (char*)sBl + ldsb);
    }
    __syncthreads();
    short8 ah[4], al[4], bh[4], bl[4];
#pragma unroll
    for (int mi = 0; mi < 4; ++mi) {
      ah[mi] = *(const short8*)(sAh + (wr * 64 + mi * 16 + lr) * 32 + lq * 8);
      al[mi] = *(const short8*)(sAl + (wr * 64 + mi * 16 + lr) * 32 + lq * 8);
    }
#pragma unroll
    for (int ni = 0; ni < 4; ++ni) {
      bh[ni] = *(const short8*)(sBh + (wc * 64 + ni * 16 + lr) * 32 + lq * 8);
      bl[ni] = *(const short8*)(sBl + (wc * 64 + ni * 16 + lr) * 32 + lq * 8);
    }
#pragma unroll
    for (int mi = 0; mi < 4; ++mi)
#pragma unroll
      for (int ni = 0; ni < 4; ++ni) {
        acc[mi][ni] = MFMA16(ah[mi], bh[ni], acc[mi][ni], 0, 0, 0);
        acc[mi][ni] = MFMA16(ah[mi], bl[ni], acc[mi][ni], 0, 0, 0);
        acc[mi][ni] = MFMA16(al[mi], bh[ni], acc[mi][ni], 0, 0, 0);
      }
    __syncthreads();
  }

  // ---- full-column softmax (rows i distributed over wr,mi,lq,r)
  float M[4];
#pragma unroll
  for (int ni = 0; ni < 4; ++ni) {
    const int jl = wc * 64 + ni * 16 + lr;
    float m = acc[0][ni][0];
#pragma unroll
    for (int mi = 0; mi < 4; ++mi)
#pragma unroll
      for (int r = 0; r < 4; ++r) m = fmaxf(m, acc[mi][ni][r]);
    m = fmaxf(m, __shfl_xor(m, 16));
    m = fmaxf(m, __shfl_xor(m, 32));
    if (lq == 0) cmax[wr][jl] = m;
  }
  __syncthreads();
#pragma unroll
  for (int ni = 0; ni < 4; ++ni) {
    const int jl = wc * 64 + ni * 16 + lr;
    M[ni] = fmaxf(fmaxf(cmax[0][jl], cmax[1][jl]), fmaxf(cmax[2][jl], cmax[3][jl]));
    float s = 0.f;
#pragma unroll
    for (int mi = 0; mi < 4; ++mi)
#pragma unroll
      for (int r = 0; r < 4; ++r) {
        float e = __expf(acc[mi][ni][r] - M[ni]);
        acc[mi][ni][r] = e; s += e;
      }
    s += __shfl_xor(s, 16);
    s += __shfl_xor(s, 32);
    if (lq == 0) csum[wr][jl] = s;
  }
  __syncthreads();
#pragma unroll
  for (int ni = 0; ni < 4; ++ni) {
    const int jl = wc * 64 + ni * 16 + lr;
    const float rs = 1.f / (csum[0][jl] + csum[1][jl] + csum[2][jl] + csum[3][jl]);
#pragma unroll
    for (int mi = 0; mi < 4; ++mi) {
      u32 w0 = cvtpk(acc[mi][ni][0] * rs, acc[mi][ni][1] * rs);
      u32 w1 = cvtpk(acc[mi][ni][2] * rs, acc[mi][ni][3] * rs);
      *(u32x2*)(Pt + cb + (size_t)(jt * 128 + jl) * 256 + wr * 64 + mi * 16 + lq * 4)
          = (u32x2){w0, w1};
    }
  }
}

// ---------------------------------------------------------------------------
// attn: out[c,i,j] = x[c,i,j] + sum_k h[c,i,k] * PT[c,j,k]. Plain bf16,
// both operands gload_lds, residual fused.
// ---------------------------------------------------------------------------
__global__ __launch_bounds__(256)
void attn_kernel(const u16* __restrict__ hb, const u16* __restrict__ Pt,
                 const float* __restrict__ x, float* __restrict__ out)
{
  __shared__ u16 sA[128 * 32], sB[128 * 32];
  const int bid = blockIdx.x;
  const int wg = (bid & 7) * 256 + (bid >> 3); // 2048%8==0
  const int c = wg >> 2, tm = (wg >> 1) & 1, tn = wg & 1;
  const int t = threadIdx.x, lane = t & 63, wid = t >> 6;
  const int wr = wid >> 1, wc = wid & 1, lr = lane & 15, lq = lane >> 4;
  const size_t cb = (size_t)c * 65536;
  const int grl = t >> 2, gko = t & 3;
  const int ldsb = wid * 1024;

  f32x4 acc[4][4];
#pragma unroll
  for (int i = 0; i < 4; ++i)
#pragma unroll
    for (int j = 0; j < 4; ++j) acc[i][j] = (f32x4){0.f, 0.f, 0.f, 0.f};

  for (int k0 = 0; k0 < 256; k0 += 32) {
#pragma unroll
    for (int q = 0; q < 2; ++q) {
      const int row = q * 64 + grl;
      gload16(hb + cb + (size_t)(tm * 128 + row) * 256 + k0 + gko * 8,
              (char*)sA + q * 4096 + ldsb);
      gload16(Pt + cb + (size_t)(tn * 128 + row) * 256 + k0 + gko * 8,
              (char*)sB + q * 4096 + ldsb);
    }
    __syncthreads();
    short8 af[4], bfr[4];
#pragma unroll
    for (int mi = 0; mi < 4; ++mi)
      af[mi] = *(const short8*)(sA + (wr * 64 + mi * 16 + lr) * 32 + lq * 8);
#pragma unroll
    for (int ni = 0; ni < 4; ++ni)
      bfr[ni] = *(const short8*)(sB + (wc * 64 + ni * 16 + lr) * 32 + lq * 8);
#pragma unroll
    for (int mi = 0; mi < 4; ++mi)
#pragma unroll
      for (int ni = 0; ni < 4; ++ni)
        acc[mi][ni] = MFMA16(af[mi], bfr[ni], acc[mi][ni], 0, 0, 0);
    __syncthreads();
  }

  const float* Xc = x + cb;
  float* Oc = out + cb;
  const int rb = tm * 128 + wr * 64, cbase = tn * 128 + wc * 64;
#pragma unroll
  for (int mi = 0; mi < 4; ++mi)
#pragma unroll
    for (int ni = 0; ni < 4; ++ni) {
      const int r0 = rb + mi * 16 + lq * 4, cc = cbase + ni * 16 + lr;
#pragma unroll
      for (int r = 0; r < 4; ++r) {
        const size_t idx = (size_t)(r0 + r) * 256 + cc;
        Oc[idx] = Xc[idx] + acc[mi][ni][r];
      }
    }
}

// ---------------------------------------------------------------------------
extern "C" void kernel_launch(void* const* d_in, const int* in_sizes, int n_in,
                              void* d_out, int out_size, void* d_ws, size_t ws_size,
                              hipStream_t stream)
{
  (void)in_sizes; (void)n_in; (void)out_size; (void)ws_size;
  const float* x  = (const float*)d_in[0];
  const float* Wf = (const float*)d_in[1];
  const float* Wg = (const float*)d_in[2];
  const float* Wh = (const float*)d_in[3];
  float* out = (float*)d_out;
  char*  ws  = (char*)d_ws;

  // ws (256 MiB): [xhi 64][xlo 64][gThi 64][gTlo 64]; d_out hosts f hi/lo.
  u16* xhi  = (u16*)ws;
  u16* xlo  = (u16*)(ws + 67108864);
  u16* gThi = (u16*)(ws + 134217728);
  u16* gTlo = (u16*)(ws + 201326592);
  u16* fhi  = (u16*)d_out;
  u16* flo  = (u16*)d_out + 33554432;
  u16* hb   = xlo;   // h overwrites xlo after conv_fg
  u16* Pt   = xhi;   // PT overwrites xhi after conv_h

  dim3 blk(256, 1, 1);
  prep_x       <<<dim3(4096, 1, 1), blk, 0, stream>>>(x, xhi, xlo);
  conv_fg      <<<dim3(4096, 1, 1), blk, 0, stream>>>(Wf, Wg, xhi, xlo, fhi, flo, gThi, gTlo);
  conv_h       <<<dim3(2048, 1, 1), blk, 0, stream>>>(Wh, xhi, hb);
  scores_kernel<<<dim3(1024, 1, 1), dim3(512, 1, 1), 0, stream>>>(fhi, flo, gThi, gTlo, Pt);
  attn_kernel  <<<dim3(2048, 1, 1), blk, 0, stream>>>(hb, Pt, x, out);
}